// Round 7
// baseline (6384.642 us; speedup 1.0000x reference)
//
#include <hip/hip_runtime.h>
#include <math.h>

typedef long long i64;
typedef __attribute__((ext_vector_type(8))) short bf16x8;
typedef __attribute__((ext_vector_type(4))) float f32x4;

#define H_DIM 600
#define L_DIM 1024
#define B_DIM 16
#define N_ST  64

// fp32 -> bf16, round-to-nearest-even (truncation would bias K=600 dot products)
__device__ __forceinline__ unsigned short f2bf(float f) {
  unsigned u = __float_as_uint(f);
  u += 0x7FFFu + ((u >> 16) & 1u);
  return (unsigned short)(u >> 16);
}

union Pack8 {
  bf16x8 v;
  unsigned long long q[2];
  unsigned short u[8];
};

// ---------------------------------------------------------------------------
// Generic strided GEMM on MFMA 16x16x32 bf16 (fp32 in/out, bf16 staging).
// C[m,n] (+)= sum_k A[m,k]*B[k,n]
//   A addr: m*sa_m + (m>>10)*a_extra + k*sa_k    (zero if (m&1023) < a_m_lo)
//   B addr: k*sb_k + n*sb_n
//   C addr: m*sc_m + (m>>10)*c_extra + n*sc_n    (Res uses same addressing)
// Batch dim folded into M (m = b*1024 + l).
// flags: 1=+bias[n], 2=relu(final), 4=accumulate into C, 8=+Res, 16=relu
// BEFORE Res add. Order: +C -> +bias -> (16?)relu -> +Res -> (2?)relu
// A/B fragments use the SAME lane->k map (contraction correct for any
// bijective k permutation); C/D map is HW-verified col=lane&15,
// row=(lane>>4)*4+reg.
// ---------------------------------------------------------------------------
__global__ __launch_bounds__(256)
void gemm_mfma(const float* __restrict__ Ap, const float* __restrict__ Bp,
               const float* __restrict__ bias, const float* __restrict__ Res,
               float* __restrict__ Cp,
               int M, int N, int K,
               int sa_m, int sa_k, i64 a_extra, int a_m_lo,
               int sb_k, int sb_n,
               int sc_m, int sc_n, i64 c_extra,
               int flags)
{
  __shared__ unsigned short As[64][36];   // 72B rows: 8B-aligned, conflict-lite
  __shared__ unsigned short Bs[64][36];

  const int tid = threadIdx.x;
  const int m0 = blockIdx.x * 64, n0 = blockIdx.y * 64;

  const int w  = tid >> 6, l = tid & 63;
  const int mq = (w & 1) << 5;          // wave's 32-row half
  const int nq = (w >> 1) << 5;         // wave's 32-col half
  const int fr = l & 15;                // fragment row/col index
  const int fk = (l >> 4) << 3;         // fragment k offset (8 bf16)

  f32x4 acc[2][2] = {};

  for (int k0 = 0; k0 < K; k0 += 32) {
    // ---- stage A (64m x 32k) ----
    if (sa_k != 1) {
      // m-contiguous global (activations): coalesced loads, vector LDS write
      const int mm = tid & 63, kb = (tid >> 6) << 3;
      const int mg = m0 + mm;
      const bool mok = (mg < M) && ((mg & 1023) >= a_m_lo);
      const float* ap = Ap + (i64)mg * sa_m + (i64)(mg >> 10) * a_extra;
      Pack8 pk;
      #pragma unroll
      for (int j = 0; j < 8; ++j) {
        const int k = k0 + kb + j;
        const float v = (mok && k < K) ? ap[(i64)k * sa_k] : 0.f;
        pk.u[j] = f2bf(v);
      }
      *(unsigned long long*)&As[mm][kb]     = pk.q[0];
      *(unsigned long long*)&As[mm][kb + 4] = pk.q[1];
    } else {
      // k-contiguous global (encoder input, s4_Wdec): coalesced along k
      #pragma unroll
      for (int p = 0; p < 8; ++p) {
        const int mr = (tid >> 5) + (p << 3);
        const int mg = m0 + mr;
        const int k  = k0 + (tid & 31);
        const bool ok = (mg < M) && ((mg & 1023) >= a_m_lo) && (k < K);
        const float v = ok ? Ap[(i64)mg * sa_m + (i64)(mg >> 10) * a_extra + k] : 0.f;
        As[mr][tid & 31] = f2bf(v);
      }
    }
    // ---- stage B (64n x 32k) ----
    {
      const int nn = tid & 63, kb = (tid >> 6) << 3;
      const int ng = n0 + nn;
      const float* bp = Bp + (i64)ng * sb_n;
      Pack8 pk;
      #pragma unroll
      for (int j = 0; j < 8; ++j) {
        const int k = k0 + kb + j;
        const float v = (ng < N && k < K) ? bp[(i64)k * sb_k] : 0.f;
        pk.u[j] = f2bf(v);
      }
      *(unsigned long long*)&Bs[nn][kb]     = pk.q[0];
      *(unsigned long long*)&Bs[nn][kb + 4] = pk.q[1];
    }
    __syncthreads();
    // ---- fragments + MFMA ----
    Pack8 a0, a1, b0, b1;
    a0.q[0] = *(const unsigned long long*)&As[mq + fr][fk];
    a0.q[1] = *(const unsigned long long*)&As[mq + fr][fk + 4];
    a1.q[0] = *(const unsigned long long*)&As[mq + 16 + fr][fk];
    a1.q[1] = *(const unsigned long long*)&As[mq + 16 + fr][fk + 4];
    b0.q[0] = *(const unsigned long long*)&Bs[nq + fr][fk];
    b0.q[1] = *(const unsigned long long*)&Bs[nq + fr][fk + 4];
    b1.q[0] = *(const unsigned long long*)&Bs[nq + 16 + fr][fk];
    b1.q[1] = *(const unsigned long long*)&Bs[nq + 16 + fr][fk + 4];
    acc[0][0] = __builtin_amdgcn_mfma_f32_16x16x32_bf16(a0.v, b0.v, acc[0][0], 0, 0, 0);
    acc[0][1] = __builtin_amdgcn_mfma_f32_16x16x32_bf16(a0.v, b1.v, acc[0][1], 0, 0, 0);
    acc[1][0] = __builtin_amdgcn_mfma_f32_16x16x32_bf16(a1.v, b0.v, acc[1][0], 0, 0, 0);
    acc[1][1] = __builtin_amdgcn_mfma_f32_16x16x32_bf16(a1.v, b1.v, acc[1][1], 0, 0, 0);
    __syncthreads();
  }

  // ---- epilogue: C/D map col=lane&15, row=(lane>>4)*4+reg ----
  const int rb = (l >> 4) << 2;
  const int cc = l & 15;
  #pragma unroll
  for (int fi = 0; fi < 2; ++fi) {
    #pragma unroll
    for (int fj = 0; fj < 2; ++fj) {
      const int mrow = m0 + mq + fi * 16 + rb;
      const int ncol = n0 + nq + fj * 16 + cc;
      if (ncol >= N || mrow >= M) continue;
      const f32x4 av = acc[fi][fj];
      if (sc_m == 1) {          // 4 consecutive m -> float4 (M multiple of 64 here)
        const i64 base = (i64)mrow + (i64)(mrow >> 10) * c_extra + (i64)ncol * sc_n;
        float4 v; v.x = av[0]; v.y = av[1]; v.z = av[2]; v.w = av[3];
        if (flags & 4) {
          const float4 o = *(const float4*)(Cp + base);
          v.x += o.x; v.y += o.y; v.z += o.z; v.w += o.w;
        }
        if (flags & 1) {
          const float bb = bias[ncol];
          v.x += bb; v.y += bb; v.z += bb; v.w += bb;
        }
        if (flags & 16) {
          v.x = fmaxf(v.x, 0.f); v.y = fmaxf(v.y, 0.f);
          v.z = fmaxf(v.z, 0.f); v.w = fmaxf(v.w, 0.f);
        }
        if (flags & 8) {
          const float4 r = *(const float4*)(Res + base);
          v.x += r.x; v.y += r.y; v.z += r.z; v.w += r.w;
        }
        if (flags & 2) {
          v.x = fmaxf(v.x, 0.f); v.y = fmaxf(v.y, 0.f);
          v.z = fmaxf(v.z, 0.f); v.w = fmaxf(v.w, 0.f);
        }
        *(float4*)(Cp + base) = v;
      } else {
        #pragma unroll
        for (int r = 0; r < 4; ++r) {
          const int m = mrow + r;
          if (m >= M) break;
          const i64 addr = (i64)m * sc_m + (i64)(m >> 10) * c_extra + (i64)ncol * sc_n;
          float vv = av[r];
          if (flags & 4)  vv += Cp[addr];
          if (flags & 1)  vv += bias[ncol];
          if (flags & 16) vv = fmaxf(vv, 0.f);
          if (flags & 8)  vv += Res[addr];
          if (flags & 2)  vv = fmaxf(vv, 0.f);
          Cp[addr] = vv;
        }
      }
    }
  }
}

// wT[lv][kt][i][o] = w[lv][o][i][kt]  over (4,600,600,3); coalesced writes
__global__ __launch_bounds__(256)
void transpose_tcn(const float* __restrict__ w, float* __restrict__ wT)
{
  const i64 idx = (i64)blockIdx.x * 256 + threadIdx.x;  // 4*3*600*600 = 4,320,000
  int t = (int)(idx / 600);
  const int n = (int)(idx % 600);
  const int k = t % 600; t /= 600;
  const int kt = t % 3;  const int lv = t / 3;
  wT[idx] = w[(((i64)lv * 600 + n) * 600 + k) * 3 + kt];
}

// woutT[lv][h][o] = Wout[lv][o][h]  over (4,1200,600)
__global__ __launch_bounds__(256)
void transpose_wout(const float* __restrict__ w, float* __restrict__ wT)
{
  const i64 idx = (i64)blockIdx.x * 256 + threadIdx.x;  // 4*600*1200 = 2,880,000
  const int o = (int)(idx % 1200);
  int t = (int)(idx / 1200);
  const int h = t % 600; const int lv = t / 600;
  wT[idx] = w[((i64)lv * 1200 + o) * 600 + h];
}

// ---------------------------------------------------------------------------
// S4D diagonal SSM as a linear recurrence. One wave per (b,h); lane = state n.
// s_l = r*s_{l-1} + u_l ;  y_l = gelu(2*Re(sum_n C2_n s_n,l) + D*u_l)
// Identical math to the reference's Vandermonde-kernel + FFT causal conv.
// ---------------------------------------------------------------------------
__global__ __launch_bounds__(256)
void s4_recur(const float* __restrict__ x, float* __restrict__ y,
              const float* __restrict__ log_dt,
              const float* __restrict__ A_re, const float* __restrict__ A_im,
              const float* __restrict__ C_re, const float* __restrict__ C_im,
              const float* __restrict__ Dv)
{
  const int wid  = blockIdx.x * 4 + (threadIdx.x >> 6);
  const int lane = threadIdx.x & 63;
  const int b = wid / H_DIM, h = wid % H_DIM;

  const float dt = expf(log_dt[h]);
  const int   pi = h * N_ST + lane;
  const float ar = A_re[pi], ai = A_im[pi];
  const float cr = C_re[pi], ci = C_im[pi];
  const float er = expf(ar * dt);
  const float rc = er * cosf(ai * dt);
  const float rs = er * sinf(ai * dt);
  const float nr = rc - 1.0f, ni = rs;
  const float inv = 1.0f / fmaf(ar, ar, ai * ai);
  const float qr = fmaf(nr, ar,  ni * ai) * inv;
  const float qi = fmaf(ni, ar, -nr * ai) * inv;
  const float c2r = fmaf(cr, qr, -ci * qi);
  const float c2i = fmaf(cr, qi,  ci * qr);
  const float Dh = Dv[h];

  const float* xp = x + ((i64)b * H_DIM + h) * L_DIM;
  float*       yp = y + ((i64)b * H_DIM + h) * L_DIM;

  float sr = 0.f, si = 0.f;
  for (int l0 = 0; l0 < L_DIM; l0 += 64) {
    const float xv = xp[l0 + lane];
    float yreg = 0.f;
    #pragma unroll 8
    for (int j = 0; j < 64; ++j) {
      const float u = __shfl(xv, j, 64);
      float trr = fmaf(rc, sr, u);
      trr = fmaf(-rs, si, trr);
      const float tii = fmaf(rc, si, rs * sr);
      sr = trr; si = tii;
      float c = fmaf(c2r, sr, -(c2i * si));
      #pragma unroll
      for (int off = 32; off; off >>= 1)
        c += __shfl_xor(c, off, 64);
      if (lane == j) yreg = c;
    }
    const float v = fmaf(2.f, yreg, Dh * xv);
    yp[l0 + lane] = 0.5f * v * (1.0f + erff(v * 0.7071067811865476f));
  }
}

// ---------------------------------------------------------------------------
// GLU: z1 = z1 * sigmoid(z2), in place on z of shape (B, 2H, L)
// ---------------------------------------------------------------------------
__global__ __launch_bounds__(256)
void glu_kernel(float* __restrict__ z)
{
  const i64 HL = (i64)H_DIM * L_DIM;
  const int b    = blockIdx.x / 600;
  const int rblk = blockIdx.x % 600;
  const i64 r = ((i64)rblk * 256 + threadIdx.x) * 4;
  float* z1 = z + (i64)b * 2 * HL + r;
  const float* z2 = z + (i64)b * 2 * HL + HL + r;
  const float4 a = *(const float4*)z1;
  const float4 g = *(const float4*)z2;
  float4 o;
  o.x = a.x / (1.f + expf(-g.x));
  o.y = a.y / (1.f + expf(-g.y));
  o.z = a.z / (1.f + expf(-g.z));
  o.w = a.w / (1.f + expf(-g.w));
  *(float4*)z1 = o;
}

// ---------------------------------------------------------------------------
// cur = LayerNorm_channels(z1 + cur) * gamma + beta   (z2 half used as scratch)
// ---------------------------------------------------------------------------
__global__ __launch_bounds__(256)
void add_ln(float* __restrict__ z, float* __restrict__ cur,
            const float* __restrict__ gamma, const float* __restrict__ beta)
{
  const int b  = blockIdx.y;
  const int lt = threadIdx.x & 63;
  const int l  = blockIdx.x * 64 + lt;
  const int hg = threadIdx.x >> 6;
  const i64 HL = (i64)H_DIM * L_DIM;
  float* z1 = z + (i64)b * 2 * HL;
  float* z2 = z1 + HL;
  float* cb = cur + (i64)b * HL;

  __shared__ float s_sum[4][64], s_sq[4][64];
  __shared__ float s_mu[64], s_rs[64];

  float sum = 0.f, sq = 0.f;
  for (int h = hg; h < H_DIM; h += 4) {
    const i64 idx = (i64)h * L_DIM + l;
    const float v = z1[idx] + cb[idx];
    z2[idx] = v;
    sum += v;
    sq = fmaf(v, v, sq);
  }
  s_sum[hg][lt] = sum;
  s_sq[hg][lt]  = sq;
  __syncthreads();
  if (hg == 0) {
    const float s = s_sum[0][lt] + s_sum[1][lt] + s_sum[2][lt] + s_sum[3][lt];
    const float q = s_sq[0][lt]  + s_sq[1][lt]  + s_sq[2][lt]  + s_sq[3][lt];
    const float mu  = s * (1.0f / H_DIM);
    const float var = q * (1.0f / H_DIM) - mu * mu;
    s_mu[lt] = mu;
    s_rs[lt] = 1.0f / sqrtf(var + 1e-5f);
  }
  __syncthreads();
  const float mu = s_mu[lt], rstd = s_rs[lt];
  for (int h = hg; h < H_DIM; h += 4) {
    const i64 idx = (i64)h * L_DIM + l;
    const float v = z2[idx];
    cb[idx] = (v - mu) * rstd * gamma[h] + beta[h];
  }
}

// bcomb[c] = sum_h s4_bdec[h] * W_dec[h,c] + b_dec[c]
__global__ __launch_bounds__(256)
void bcomb_kernel(const float* __restrict__ s4_bdec, const float* __restrict__ W_dec,
                  const float* __restrict__ b_dec, float* __restrict__ bcomb)
{
  const int c = blockIdx.x * 256 + threadIdx.x;
  if (c >= 257) return;
  float acc = b_dec[c];
  for (int h = 0; h < H_DIM; ++h)
    acc = fmaf(s4_bdec[h], W_dec[h * 257 + c], acc);
  bcomb[c] = acc;
}

// ---------------------------------------------------------------------------
extern "C" void kernel_launch(void* const* d_in, const int* in_sizes, int n_in,
                              void* d_out, int out_size, void* d_ws, size_t ws_size,
                              hipStream_t stream)
{
  const float* input    = (const float*)d_in[0];
  const float* W_enc    = (const float*)d_in[1];
  const float* b_enc    = (const float*)d_in[2];
  const float* tcn_w1   = (const float*)d_in[3];
  const float* tcn_b1   = (const float*)d_in[4];
  const float* tcn_w2   = (const float*)d_in[5];
  const float* tcn_b2   = (const float*)d_in[6];
  const float* s4_Wenc  = (const float*)d_in[7];
  const float* s4_benc  = (const float*)d_in[8];
  const float* s4_logdt = (const float*)d_in[9];
  const float* s4_A_re  = (const float*)d_in[10];
  const float* s4_A_im  = (const float*)d_in[11];
  const float* s4_C_re  = (const float*)d_in[12];
  const float* s4_C_im  = (const float*)d_in[13];
  const float* s4_D     = (const float*)d_in[14];
  const float* s4_Wout  = (const float*)d_in[15];
  const float* s4_bout  = (const float*)d_in[16];
  const float* ln_g     = (const float*)d_in[17];
  const float* ln_b     = (const float*)d_in[18];
  const float* s4_Wdec  = (const float*)d_in[19];
  const float* s4_bdec  = (const float*)d_in[20];
  const float* W_dec    = (const float*)d_in[21];
  const float* b_dec    = (const float*)d_in[22];
  float* out = (float*)d_out;

  const i64 HL  = (i64)H_DIM * L_DIM;     // 614400
  const i64 BHL = (i64)B_DIM * HL;        // 9830400
  const i64 AE  = HL - 1024;              // (B,H,L) per-batch extra stride
  const int MM  = B_DIM * L_DIM;          // 16384: batch folded into M
  float* buf0  = (float*)d_ws;            // (B,H,L)
  float* buf1  = buf0 + BHL;              // (B,H,L)
  float* zbuf  = buf1 + BHL;              // (B,2H,L)
  float* wcomb = zbuf + 2 * BHL;          // (600,257)
  float* bcomb = wcomb + (i64)H_DIM * 257;
  float* wT1   = bcomb + 260;             // (4,3,600,600) transposed TCN conv1
  float* wT2   = wT1 + (i64)4 * 3 * 600 * 600;
  float* woutT = wT2 + (i64)4 * 3 * 600 * 600;  // (4,600,1200)

  // transposed-weight path needs this much scratch; else fall back (branch is
  // deterministic per session -> graph-capture safe)
  const size_t need = (size_t)((woutT + (i64)4 * 600 * 1200) - buf0) * 4;
  const bool XP = ws_size >= need;

  const dim3 blk(256);

  if (XP) {
    transpose_tcn<<<dim3(16875), blk, 0, stream>>>(tcn_w1, wT1);
    transpose_tcn<<<dim3(16875), blk, 0, stream>>>(tcn_w2, wT2);
    transpose_wout<<<dim3(11250), blk, 0, stream>>>(s4_Wout, woutT);
  }

  // wcomb = s4_Wdec @ W_dec ; bcomb = s4_bdec @ W_dec + b_dec
  gemm_mfma<<<dim3(10, 5), blk, 0, stream>>>(
      s4_Wdec, W_dec, nullptr, nullptr, wcomb,
      600, 257, 600,
      600, 1, 0, 0,   257, 1,   257, 1, 0,   0);
  bcomb_kernel<<<dim3(2), blk, 0, stream>>>(s4_bdec, W_dec, b_dec, bcomb);

  // encoder: buf0[b,h,l] = sum_c input[b,l,c]*W_enc[c,h] + b_enc[h]
  gemm_mfma<<<dim3(256, 10), blk, 0, stream>>>(
      input, W_enc, b_enc, nullptr, buf0,
      MM, 600, 257,
      257, 1, 0, 0,   600, 1,   1, 1024, AE,   1);

  // ---- TCN: 4 levels, each conv = 3 shifted GEMM taps ----
  float* cur = buf0;
  for (int lv = 0; lv < 4; ++lv) {
    const int d = 1 << lv;
    float* o2 = (lv % 2 == 0) ? zbuf : buf0;
    const float* bb1 = tcn_b1 + lv * 600;
    const float* bb2 = tcn_b2 + lv * 600;
    for (int kt = 0; kt < 3; ++kt) {           // conv1: cur -> buf1, relu
      const int s = (2 - kt) * d;
      int flags = (kt == 0) ? 1 : 4;
      if (kt == 2) flags |= 2;
      const float* Bp = XP ? (wT1 + ((i64)(lv * 3 + kt)) * 600 * 600)
                           : (tcn_w1 + (i64)lv * 600 * 600 * 3 + kt);
      const int sbk = XP ? 600 : 3, sbn = XP ? 1 : 1800;
      gemm_mfma<<<dim3(256, 10), blk, 0, stream>>>(
          cur - s, Bp, bb1, nullptr, buf1,
          MM, 600, 600,
          1, 1024, AE, s,   sbk, sbn,   1, 1024, AE,   flags);
    }
    for (int kt = 0; kt < 3; ++kt) {           // conv2: relu, +res, relu
      const int s = (2 - kt) * d;
      int flags = (kt == 0) ? 1 : 4;
      if (kt == 2) flags |= 16 | 8 | 2;
      const float* Bp = XP ? (wT2 + ((i64)(lv * 3 + kt)) * 600 * 600)
                           : (tcn_w2 + (i64)lv * 600 * 600 * 3 + kt);
      const int sbk = XP ? 600 : 3, sbn = XP ? 1 : 1800;
      gemm_mfma<<<dim3(256, 10), blk, 0, stream>>>(
          buf1 - s, Bp, bb2, (kt == 2) ? cur : nullptr, o2,
          MM, 600, 600,
          1, 1024, AE, s,   sbk, sbn,   1, 1024, AE,   flags);
    }
    cur = o2;
  }
  // cur == buf0 here

  // s4 encode: buf0 -> buf1
  gemm_mfma<<<dim3(256, 10), blk, 0, stream>>>(
      buf0, s4_Wenc, s4_benc, nullptr, buf1,
      MM, 600, 600,
      1, 1024, AE, 0,   600, 1,   1, 1024, AE,   1);

  float* scur = buf1;   // residual stream
  float* sy   = buf0;   // SSM output temp
  for (int i = 0; i < 4; ++i) {
    s4_recur<<<dim3(2400), blk, 0, stream>>>(
        scur, sy,
        s4_logdt + i * 600,
        s4_A_re + (i64)i * 600 * 64, s4_A_im + (i64)i * 600 * 64,
        s4_C_re + (i64)i * 600 * 64, s4_C_im + (i64)i * 600 * 64,
        s4_D + i * 600);
    const float* Bp = XP ? (woutT + (i64)i * 600 * 1200)
                         : (s4_Wout + (i64)i * 1200 * 600);
    const int sbk = XP ? 1200 : 1, sbn = XP ? 1 : 600;
    gemm_mfma<<<dim3(256, 19), blk, 0, stream>>>(
        sy, Bp, s4_bout + i * 1200, nullptr, zbuf,
        MM, 1200, 600,
        1, 1024, AE, 0,   sbk, sbn,   1, 1024, 2 * HL - 1024,   1);
    glu_kernel<<<dim3(9600), blk, 0, stream>>>(zbuf);
    add_ln<<<dim3(16, 16), blk, 0, stream>>>(zbuf, scur, ln_g + i * 600, ln_b + i * 600);
  }

  // final: out[b,l,c] = sum_h scur[b,h,l] * wcomb[h,c] + bcomb[c]
  gemm_mfma<<<dim3(256, 5), blk, 0, stream>>>(
      scur, wcomb, bcomb, nullptr, out,
      MM, 257, 600,
      1, 1024, AE, 0,   257, 1,   257, 1, 0,   1);
}